// Round 2
// baseline (1015.748 us; speedup 1.0000x reference)
//
#include <hip/hip_runtime.h>
#include <hip/hip_bf16.h>

// GraphNet (NNConv/GRU/Set2Set) forward, MI355X.
// Strategy: fuse We=eh@e2_W into the per-step message GEMM (f16 MFMA 16x16x32,
// f32 accum), deterministic CSR aggregation, f32 everywhere else.

#define N_  8192
#define E_  32768
#define B_  64
#define D_  64
#define FN_ 32
#define FE_ 16
#define EH_ 128

typedef _Float16 half8 __attribute__((ext_vector_type(8)));
typedef float    f32x4 __attribute__((ext_vector_type(4)));

__device__ __forceinline__ float sigmf(float x) { return 1.f / (1.f + expf(-x)); }

// ---------------- pre: lin0 / BN / edge NN ----------------

__global__ __launch_bounds__(256) void k_lin0(const float* __restrict__ x,
    const float* __restrict__ W, const float* __restrict__ b, float* __restrict__ t0) {
  int gid = blockIdx.x * 256 + threadIdx.x;           // N*64
  int n = gid >> 6, d = gid & 63;
  const float* xr = x + (size_t)n * FN_;
  float a = b[d];
  #pragma unroll
  for (int i = 0; i < FN_; ++i) a += xr[i] * W[i * 64 + d];
  t0[gid] = a;
}

__global__ __launch_bounds__(256) void k_colstats(const float* __restrict__ in, int rows, int cols,
    float* __restrict__ mean, float* __restrict__ rstd) {
  int d = blockIdx.x;
  float s = 0.f, s2 = 0.f;
  for (int n = threadIdx.x; n < rows; n += 256) {
    float v = in[(size_t)n * cols + d];
    s += v; s2 += v * v;
  }
  #pragma unroll
  for (int off = 32; off; off >>= 1) { s += __shfl_xor(s, off); s2 += __shfl_xor(s2, off); }
  __shared__ float ls[4], ls2[4];
  int w = threadIdx.x >> 6;
  if ((threadIdx.x & 63) == 0) { ls[w] = s; ls2[w] = s2; }
  __syncthreads();
  if (threadIdx.x == 0) {
    float S = ls[0] + ls[1] + ls[2] + ls[3], S2 = ls2[0] + ls2[1] + ls2[2] + ls2[3];
    float mu = S / rows;
    float va = S2 / rows - mu * mu;
    mean[d] = mu;
    rstd[d] = rsqrtf(va + 1e-5f);
  }
}

__global__ __launch_bounds__(256) void k_bnrelu0(const float* __restrict__ t0,
    const float* __restrict__ mean, const float* __restrict__ rstd,
    const float* __restrict__ g, const float* __restrict__ b,
    float* __restrict__ x0, float* __restrict__ hb) {
  int gid = blockIdx.x * 256 + threadIdx.x;           // N*64
  int d = gid & 63;
  float v = fmaxf(0.f, (t0[gid] - mean[d]) * rstd[d] * g[d] + b[d]);
  x0[gid] = v; hb[gid] = v;
}

__global__ __launch_bounds__(256) void k_e1(const float* __restrict__ ea,
    const float* __restrict__ W, const float* __restrict__ b, float* __restrict__ t1) {
  int gid = blockIdx.x * 256 + threadIdx.x;           // E*128
  int n = gid >> 7, j = gid & 127;
  const float* er = ea + (size_t)n * FE_;
  float a = b[j];
  #pragma unroll
  for (int i = 0; i < FE_; ++i) a += er[i] * W[i * 128 + j];
  t1[gid] = a;
}

__global__ __launch_bounds__(256) void k_bnrelu_eh(const float* __restrict__ t1,
    const float* __restrict__ mean, const float* __restrict__ rstd,
    const float* __restrict__ g, const float* __restrict__ b, _Float16* __restrict__ ehq) {
  int gid = blockIdx.x * 256 + threadIdx.x;           // E*128
  int d = gid & 127;
  float v = fmaxf(0.f, (t1[gid] - mean[d]) * rstd[d] * g[d] + b[d]);
  ehq[gid] = (_Float16)v;
}

// pack e2_W [128,4096] f32 -> fragment-ready f16: idx (((i*4+kf)*4+nf)*64+lane)*8+j
__global__ __launch_bounds__(256) void k_w2pack(const float* __restrict__ e2W, half8* __restrict__ w2p8) {
  int t = blockIdx.x * 256 + threadIdx.x;             // 65536
  int l = t & 63, nf = (t >> 6) & 3, kf = (t >> 8) & 3, i = t >> 10;
  half8 v;
  #pragma unroll
  for (int j = 0; j < 8; ++j) {
    int k = kf * 32 + ((l >> 4) << 3) + j;
    v[j] = (_Float16)e2W[(size_t)k * 4096 + i * 64 + (nf << 4) + (l & 15)];
  }
  w2p8[t] = v;
}

// ---------------- CSR build (deterministic aggregation) ----------------

__global__ __launch_bounds__(256) void k_cnt(const int* __restrict__ dstI, int* __restrict__ cnt) {
  int e = blockIdx.x * 256 + threadIdx.x;
  atomicAdd(&cnt[dstI[e]], 1);
}

__global__ __launch_bounds__(256) void k_nodecnt(const int* __restrict__ batch, int* __restrict__ nc) {
  int n = blockIdx.x * 256 + threadIdx.x;
  atomicAdd(&nc[batch[n]], 1);
}

__global__ __launch_bounds__(1024) void k_scan(const int* __restrict__ cnt, int* __restrict__ row_start,
    int* __restrict__ cursor, float* __restrict__ cntf) {
  __shared__ int sp[1024];
  int t = threadIdx.x;
  int v[8]; int s = 0;
  #pragma unroll
  for (int j = 0; j < 8; ++j) { v[j] = cnt[t * 8 + j]; s += v[j]; }
  sp[t] = s;
  __syncthreads();
  for (int off = 1; off < 1024; off <<= 1) {
    int a = (t >= off) ? sp[t - off] : 0;
    __syncthreads();
    sp[t] += a;
    __syncthreads();
  }
  int run = sp[t] - s;                                 // exclusive prefix
  #pragma unroll
  for (int j = 0; j < 8; ++j) {
    row_start[t * 8 + j] = run;
    cursor[t * 8 + j] = run;
    cntf[t * 8 + j] = fmaxf(1.0f, (float)v[j]);
    run += v[j];
  }
  if (t == 1023) row_start[N_] = run;                  // = E
}

__global__ void k_gs(const int* __restrict__ nc, int* __restrict__ gs) {
  if (threadIdx.x == 0 && blockIdx.x == 0) {
    int a = 0;
    for (int b = 0; b < B_; ++b) { gs[b] = a; a += nc[b]; }
    gs[B_] = a;
  }
}

__global__ __launch_bounds__(256) void k_fill(const int* __restrict__ dstI, int* __restrict__ cursor,
    int* __restrict__ csr) {
  int e = blockIdx.x * 256 + threadIdx.x;
  int pos = atomicAdd(&cursor[dstI[e]], 1);
  csr[pos] = e;
}

// ---------------- per-step kernels ----------------

// P2 = xo @ reshape(e2_b,64,64); R = xo @ root_W + root_b
__global__ __launch_bounds__(256) void k_nodelin(const float* __restrict__ xo,
    const float* __restrict__ e2b, const float* __restrict__ rootW, const float* __restrict__ rootb,
    float* __restrict__ P2, float* __restrict__ R) {
  int gid = blockIdx.x * 256 + threadIdx.x;            // N*64
  int n = gid >> 6, d = gid & 63;
  const float* xr = xo + (size_t)n * 64;
  float ap = 0.f, ar = rootb[d];
  #pragma unroll 8
  for (int i = 0; i < 64; ++i) {
    float xv = xr[i];
    ap += xv * e2b[i * 64 + d];
    ar += xv * rootW[i * 64 + d];
  }
  P2[gid] = ap; R[gid] = ar;
}

// fused message: msg[e,o] = sum_i xs[e,i]*(eh[e,:]@e2_W[:, i*64+o]) + P2[src[e],o]
// block = 256 thr (4 waves), 64 edges/block; wave w owns rows [w*16, w*16+16).
__global__ __launch_bounds__(256) void k_msg(const _Float16* __restrict__ ehq,
    const half8* __restrict__ w2p8, const float* __restrict__ xo, const float* __restrict__ P2,
    const int* __restrict__ srcI, float* __restrict__ msg) {
  __shared__ half8 bbuf[2][1024];                      // double-buffered B i-slice (2x16KB)
  __shared__ float xs[64][65];                         // gathered xo[src] tile (+pad)
  __shared__ int ssrc[64];
  const int tid = threadIdx.x;
  const int lane = tid & 63;
  const int w = tid >> 6;
  const int be = blockIdx.x * 64;

  if (tid < 64) ssrc[tid] = srcI[be + tid];
  __syncthreads();
  for (int r = w; r < 64; r += 4) xs[r][lane] = xo[(size_t)ssrc[r] * 64 + lane];

  half8 A[4];                                          // eh fragments, K=128 over 4 steps
  {
    const _Float16* ap = ehq + (size_t)(be + w * 16 + (lane & 15)) * 128 + ((lane >> 4) << 3);
    #pragma unroll
    for (int kf = 0; kf < 4; ++kf) A[kf] = *(const half8*)(ap + kf * 32);
  }
  #pragma unroll
  for (int c = 0; c < 4; ++c) bbuf[0][c * 256 + tid] = w2p8[c * 256 + tid];

  f32x4 acc[4] = {{0.f,0.f,0.f,0.f},{0.f,0.f,0.f,0.f},{0.f,0.f,0.f,0.f},{0.f,0.f,0.f,0.f}};
  __syncthreads();

  for (int i = 0; i < 64; ++i) {
    half8 p[4];                                        // prefetch next i-slice to regs
    const int inext = (i < 63) ? i + 1 : 63;
    const half8* gp = w2p8 + (size_t)inext * 1024;
    #pragma unroll
    for (int c = 0; c < 4; ++c) p[c] = gp[c * 256 + tid];

    const half8* bb = bbuf[i & 1];
    f32x4 C[4] = {{0.f,0.f,0.f,0.f},{0.f,0.f,0.f,0.f},{0.f,0.f,0.f,0.f},{0.f,0.f,0.f,0.f}};
    #pragma unroll
    for (int kf = 0; kf < 4; ++kf) {
      #pragma unroll
      for (int nf = 0; nf < 4; ++nf)
        C[nf] = __builtin_amdgcn_mfma_f32_16x16x32_f16(A[kf], bb[(kf * 4 + nf) * 64 + lane], C[nf], 0, 0, 0);
    }
    {   // acc += xs[row,i] * C   (C/D layout: col=lane&15, row=(lane>>4)*4+r)
      const int rbase = w * 16 + ((lane >> 4) << 2);
      #pragma unroll
      for (int r = 0; r < 4; ++r) {
        const float s = xs[rbase + r][i];
        #pragma unroll
        for (int nf = 0; nf < 4; ++nf) acc[nf][r] += s * C[nf][r];
      }
    }
    half8* nb = bbuf[(i + 1) & 1];
    #pragma unroll
    for (int c = 0; c < 4; ++c) nb[c * 256 + tid] = p[c];
    __syncthreads();
  }

  const int rbase = w * 16 + ((lane >> 4) << 2);
  #pragma unroll
  for (int r = 0; r < 4; ++r) {
    const int row = rbase + r;
    const int e = be + row;
    const int sn = ssrc[row];
    #pragma unroll
    for (int nf = 0; nf < 4; ++nf) {
      const int col = (nf << 4) + (lane & 15);
      msg[(size_t)e * 64 + col] = acc[nf][r] + P2[(size_t)sn * 64 + col];
    }
  }
}

// m[n,:] = relu(segsum(msg)/cnt + R[n,:])  (wave per node)
__global__ __launch_bounds__(256) void k_agg(const float* __restrict__ msg, const int* __restrict__ csr,
    const int* __restrict__ row_start, const float* __restrict__ cntf,
    const float* __restrict__ R, float* __restrict__ m) {
  int lane = threadIdx.x & 63;
  int n = blockIdx.x * 4 + (threadIdx.x >> 6);
  int s0 = row_start[n], s1 = row_start[n + 1];
  float acc = 0.f;
  for (int idx = s0; idx < s1; ++idx) {
    int e = csr[idx];
    acc += msg[(size_t)e * 64 + lane];
  }
  m[(size_t)n * 64 + lane] = fmaxf(0.f, acc / cntf[n] + R[(size_t)n * 64 + lane]);
}

__global__ __launch_bounds__(256) void k_gates(const float* __restrict__ m, const float* __restrict__ h,
    const float* __restrict__ Wih, const float* __restrict__ Whh,
    const float* __restrict__ bih, const float* __restrict__ bhh,
    float* __restrict__ gi, float* __restrict__ gh) {
  int gid = blockIdx.x * 256 + threadIdx.x;            // N*192
  int n = gid / 192, j = gid % 192;
  const float* mr = m + (size_t)n * 64;
  const float* hr = h + (size_t)n * 64;
  float ai = bih[j], ah = bhh[j];
  #pragma unroll 8
  for (int d = 0; d < 64; ++d) {
    ai += mr[d] * Wih[d * 192 + j];
    ah += hr[d] * Whh[d * 192 + j];
  }
  gi[gid] = ai; gh[gid] = ah;
}

__global__ __launch_bounds__(256) void k_update(const float* __restrict__ gi, const float* __restrict__ gh,
    float* __restrict__ h) {
  int gid = blockIdx.x * 256 + threadIdx.x;            // N*64
  int n = gid >> 6, d = gid & 63;
  const float* gin = gi + (size_t)n * 192;
  const float* ghn = gh + (size_t)n * 192;
  float r = sigmf(gin[d] + ghn[d]);
  float z = sigmf(gin[64 + d] + ghn[64 + d]);
  float nn = tanhf(gin[128 + d] + r * ghn[128 + d]);
  h[gid] = (1.f - z) * nn + z * h[gid];
}

// ---------------- Set2Set ----------------

__global__ __launch_bounds__(256) void k_lstm(float* __restrict__ qs, float* __restrict__ hl,
    float* __restrict__ cl, const float* __restrict__ Wih, const float* __restrict__ Whh,
    const float* __restrict__ bih, const float* __restrict__ bhh) {
  int b = blockIdx.x, j = threadIdx.x;                 // 64 blocks x 256
  __shared__ float sqs[128], shl[64], sg[256];
  if (j < 128) sqs[j] = qs[b * 128 + j];
  if (j < 64)  shl[j] = hl[b * 64 + j];
  __syncthreads();
  float a = bih[j] + bhh[j];
  #pragma unroll 8
  for (int k = 0; k < 128; ++k) a += sqs[k] * Wih[k * 256 + j];
  #pragma unroll 8
  for (int k = 0; k < 64; ++k)  a += shl[k] * Whh[k * 256 + j];
  sg[j] = a;
  __syncthreads();
  if (j < 64) {
    float i_ = sg[j], f_ = sg[64 + j], g_ = sg[128 + j], o_ = sg[192 + j];
    float c = sigmf(f_) * cl[b * 64 + j] + sigmf(i_) * tanhf(g_);
    cl[b * 64 + j] = c;
    hl[b * 64 + j] = sigmf(o_) * tanhf(c);
  }
}

// attention: e=<xo,q>, segmax, segsum, weighted sum; writes qs=[q, rsum]
__global__ __launch_bounds__(256) void k_att(const float* __restrict__ xo, const float* __restrict__ hl,
    const int* __restrict__ gs, float* __restrict__ ebuf, float* __restrict__ qs) {
  int b = blockIdx.x;
  int lane = threadIdx.x & 63, w = threadIdx.x >> 6;
  int s0 = gs[b], s1 = gs[b + 1];
  __shared__ float red[4], ash[4], rsh[4][64];
  float q = hl[b * 64 + lane];
  float mx = -INFINITY;
  for (int n = s0 + w; n < s1; n += 4) {
    float v = xo[(size_t)n * 64 + lane] * q;
    #pragma unroll
    for (int off = 32; off; off >>= 1) v += __shfl_xor(v, off);
    if (lane == 0) ebuf[n] = v;
    mx = fmaxf(mx, v);
  }
  if (lane == 0) red[w] = mx;
  __syncthreads();
  float gmax = fmaxf(fmaxf(red[0], red[1]), fmaxf(red[2], red[3]));
  float asum = 0.f, racc = 0.f;
  for (int n = s0 + w; n < s1; n += 4) {
    float aa = expf(ebuf[n] - gmax);
    asum += aa;
    racc += aa * xo[(size_t)n * 64 + lane];
  }
  rsh[w][lane] = racc;
  if (lane == 0) ash[w] = asum;
  __syncthreads();
  if (threadIdx.x < 64) {
    int t = threadIdx.x;
    float rt = rsh[0][t] + rsh[1][t] + rsh[2][t] + rsh[3][t];
    float at = ash[0] + ash[1] + ash[2] + ash[3];
    qs[b * 128 + t] = hl[b * 64 + t];
    qs[b * 128 + 64 + t] = rt / (at + 1e-16f);
  }
}

// ---------------- head ----------------

__global__ __launch_bounds__(64) void k_head(const float* __restrict__ in, const float* __restrict__ W,
    const float* __restrict__ bias, const float* __restrict__ g, const float* __restrict__ bt,
    float* __restrict__ out, int K) {
  int c = blockIdx.x, NC = gridDim.x, r = threadIdx.x; // 64 rows, 1 wave
  const float* ir = in + (size_t)r * K;
  float v = bias[c];
  for (int k = 0; k < K; ++k) v += ir[k] * W[k * NC + c];
  float s = v, s2 = v * v;
  #pragma unroll
  for (int off = 32; off; off >>= 1) { s += __shfl_xor(s, off); s2 += __shfl_xor(s2, off); }
  float mu = s * (1.f / 64.f);
  float va = s2 * (1.f / 64.f) - mu * mu;
  out[(size_t)r * NC + c] = fmaxf(0.f, (v - mu) * rsqrtf(va + 1e-5f) * g[c] + bt[c]);
}

__global__ __launch_bounds__(64) void k_out(const float* __restrict__ y3, const float* __restrict__ foW,
    const float* __restrict__ fob, float* __restrict__ out) {
  int b = threadIdx.x;
  float v = fob[0];
  #pragma unroll
  for (int k = 0; k < 32; ++k) v += y3[b * 32 + k] * foW[k];
  out[b] = v;
}

// ---------------- host ----------------

extern "C" void kernel_launch(void* const* d_in, const int* in_sizes, int n_in,
                              void* d_out, int out_size, void* d_ws, size_t ws_size,
                              hipStream_t stream) {
  (void)in_sizes; (void)n_in; (void)out_size; (void)ws_size;
  const float* x      = (const float*)d_in[0];
  const float* eattr  = (const float*)d_in[1];
  const int*   ei     = (const int*)d_in[2];
  const int*   batch  = (const int*)d_in[3];
  const float* lin0_W = (const float*)d_in[4];
  const float* lin0_b = (const float*)d_in[5];
  const float* bn0_g  = (const float*)d_in[6];
  const float* bn0_b  = (const float*)d_in[7];
  const float* e1_W   = (const float*)d_in[8];
  const float* e1_b   = (const float*)d_in[9];
  const float* ebn_g  = (const float*)d_in[10];
  const float* ebn_b  = (const float*)d_in[11];
  const float* e2_W   = (const float*)d_in[12];
  const float* e2_b   = (const float*)d_in[13];
  const float* root_W = (const float*)d_in[14];
  const float* root_b = (const float*)d_in[15];
  const float* gWih   = (const float*)d_in[16];
  const float* gWhh   = (const float*)d_in[17];
  const float* gbih   = (const float*)d_in[18];
  const float* gbhh   = (const float*)d_in[19];
  const float* lWih   = (const float*)d_in[20];
  const float* lWhh   = (const float*)d_in[21];
  const float* lbih   = (const float*)d_in[22];
  const float* lbhh   = (const float*)d_in[23];
  const float* f1_W   = (const float*)d_in[24];
  const float* f1_b   = (const float*)d_in[25];
  const float* f1_g   = (const float*)d_in[26];
  const float* f1_bt  = (const float*)d_in[27];
  const float* f2_W   = (const float*)d_in[28];
  const float* f2_b   = (const float*)d_in[29];
  const float* f2_g   = (const float*)d_in[30];
  const float* f2_bt  = (const float*)d_in[31];
  const float* f3_W   = (const float*)d_in[32];
  const float* f3_b   = (const float*)d_in[33];
  const float* f3_g   = (const float*)d_in[34];
  const float* f3_bt  = (const float*)d_in[35];
  const float* fo_W   = (const float*)d_in[36];
  const float* fo_b   = (const float*)d_in[37];
  const int* srcI = ei;
  const int* dstI = ei + E_;

  char* base = (char*)d_ws;
  size_t off = 0;
  auto alloc = [&](size_t bytes) -> void* {
    off = (off + 255) & ~(size_t)255;
    void* p = base + off;
    off += bytes;
    return p;
  };
  float* t0    = (float*)alloc((size_t)N_ * 64 * 4);
  float* t1    = (float*)alloc((size_t)E_ * 128 * 4);
  float* x0    = (float*)alloc((size_t)N_ * 64 * 4);
  float* hb    = (float*)alloc((size_t)N_ * 64 * 4);
  _Float16* ehq = (_Float16*)alloc((size_t)E_ * 128 * 2);
  half8* w2p8  = (half8*)alloc((size_t)65536 * 16);
  float* P2    = (float*)alloc((size_t)N_ * 64 * 4);
  float* R     = (float*)alloc((size_t)N_ * 64 * 4);
  float* mbuf  = (float*)alloc((size_t)N_ * 64 * 4);
  float* gi    = (float*)alloc((size_t)N_ * 192 * 4);
  float* gh    = (float*)alloc((size_t)N_ * 192 * 4);
  float* msg   = (float*)alloc((size_t)E_ * 64 * 4);
  int* cnt_i   = (int*)alloc((size_t)N_ * 4);
  int* cursor  = (int*)alloc((size_t)N_ * 4);
  int* row_start = (int*)alloc((size_t)(N_ + 1) * 4);
  int* csr     = (int*)alloc((size_t)E_ * 4);
  float* cntf  = (float*)alloc((size_t)N_ * 4);
  int* nodecnt = (int*)alloc(64 * 4);
  int* gs      = (int*)alloc(65 * 4);
  float* mean0 = (float*)alloc(64 * 4);
  float* rstd0 = (float*)alloc(64 * 4);
  float* meanE = (float*)alloc(128 * 4);
  float* rstdE = (float*)alloc(128 * 4);
  float* qhc   = (float*)alloc((size_t)B_ * (128 + 64 + 64) * 4);  // qs|hl|cl
  float* qs    = qhc;
  float* hl    = qhc + B_ * 128;
  float* cl    = hl + B_ * 64;
  float* ebuf  = (float*)alloc((size_t)N_ * 4);
  float* y1    = (float*)alloc((size_t)B_ * 256 * 4);
  float* y2    = (float*)alloc((size_t)B_ * 128 * 4);
  float* y3    = (float*)alloc((size_t)B_ * 32 * 4);

  hipMemsetAsync(cnt_i, 0, (size_t)N_ * 4, stream);
  hipMemsetAsync(nodecnt, 0, 64 * 4, stream);
  hipMemsetAsync(qhc, 0, (size_t)B_ * 256 * 4, stream);

  // preprocessing
  k_lin0<<<N_ * 64 / 256, 256, 0, stream>>>(x, lin0_W, lin0_b, t0);
  k_colstats<<<64, 256, 0, stream>>>(t0, N_, 64, mean0, rstd0);
  k_bnrelu0<<<N_ * 64 / 256, 256, 0, stream>>>(t0, mean0, rstd0, bn0_g, bn0_b, x0, hb);
  k_e1<<<E_ * 128 / 256, 256, 0, stream>>>(eattr, e1_W, e1_b, t1);
  k_colstats<<<128, 256, 0, stream>>>(t1, E_, 128, meanE, rstdE);
  k_bnrelu_eh<<<E_ * 128 / 256, 256, 0, stream>>>(t1, meanE, rstdE, ebn_g, ebn_b, ehq);
  k_w2pack<<<256, 256, 0, stream>>>(e2_W, w2p8);
  k_cnt<<<E_ / 256, 256, 0, stream>>>(dstI, cnt_i);
  k_nodecnt<<<N_ / 256, 256, 0, stream>>>(batch, nodecnt);
  k_scan<<<1, 1024, 0, stream>>>(cnt_i, row_start, cursor, cntf);
  k_gs<<<1, 1, 0, stream>>>(nodecnt, gs);
  k_fill<<<E_ / 256, 256, 0, stream>>>(dstI, cursor, csr);

  // 4 message passes
  const float* xo = x0;
  for (int s = 0; s < 4; ++s) {
    k_nodelin<<<N_ * 64 / 256, 256, 0, stream>>>(xo, e2_b, root_W, root_b, P2, R);
    k_msg<<<E_ / 64, 256, 0, stream>>>(ehq, w2p8, xo, P2, srcI, msg);
    k_agg<<<N_ / 4, 256, 0, stream>>>(msg, csr, row_start, cntf, R, mbuf);
    k_gates<<<N_ * 192 / 256, 256, 0, stream>>>(mbuf, hb, gWih, gWhh, gbih, gbhh, gi, gh);
    k_update<<<N_ * 64 / 256, 256, 0, stream>>>(gi, gh, hb);
    xo = hb;
  }

  // Set2Set (xo = final h = hb)
  for (int it = 0; it < 5; ++it) {
    k_lstm<<<B_, 256, 0, stream>>>(qs, hl, cl, lWih, lWhh, lbih, lbhh);
    k_att<<<B_, 256, 0, stream>>>(hb, hl, gs, ebuf, qs);
  }

  // head
  k_head<<<256, 64, 0, stream>>>(qs, f1_W, f1_b, f1_g, f1_bt, y1, 128);
  k_head<<<128, 64, 0, stream>>>(y1, f2_W, f2_b, f2_g, f2_bt, y2, 256);
  k_head<<<32, 64, 0, stream>>>(y2, f3_W, f3_b, f3_g, f3_bt, y3, 128);
  k_out<<<1, 64, 0, stream>>>(y3, fo_W, fo_b, (float*)d_out);
}